// Round 18
// baseline (135.427 us; speedup 1.0000x reference)
//
#include <hip/hip_runtime.h>
#include <hip/hip_bf16.h>
#include <float.h>

using bf16 = __hip_bfloat16;
typedef __attribute__((ext_vector_type(8))) short bf16x8;
typedef __attribute__((ext_vector_type(4))) float f32x4;
typedef __attribute__((ext_vector_type(16))) float f32x16;

#define DIM   1024
#define NSEQ  4096
#define BATCH 2
#define NH    16
#define HD    64
#define NSEG  8
#define MSEG  512
#define ROWS  (BATCH*NSEQ)   // 8192
#define NC    (BATCH*NH)     // 32
#define QSCALE (0.125f * 1.44269504f)   // d^-0.5 * log2(e)  (exp2 softmax)

__device__ __forceinline__ float fast_exp2(float x) {
    float r;
    asm volatile("v_exp_f32 %0, %1" : "=v"(r) : "v"(x));
    return r;
}

__device__ __forceinline__ void gload16(const bf16* g, bf16* l) {
    __builtin_amdgcn_global_load_lds((const __attribute__((address_space(1))) unsigned int*)g,
                                     (__attribute__((address_space(3))) unsigned int*)l, 16, 0, 0);
}

// ------------- fused prep: x->bf16 convert | 4x weight transpose | rope table
__global__ void k_prep(const float* __restrict__ x, bf16* __restrict__ Xb,
                       const float* __restrict__ Wq, const float* __restrict__ Wkv,
                       const float* __restrict__ Wo, const float* __restrict__ Wo0,
                       bf16* __restrict__ WqT, bf16* __restrict__ WkvT,
                       bf16* __restrict__ WoT, bf16* __restrict__ Wo0T,
                       float* __restrict__ cosT, float* __restrict__ sinT) {
    __shared__ float tile[32][33];
    int b = blockIdx.x, tid = threadIdx.x;
    if (b < 8192) {
        int i = (b * 256 + tid) * 4;
        float4 v = *(const float4*)&x[i];
        union { bf16 h[4]; uint2 u; } p;
        p.h[0] = __float2bfloat16(v.x);
        p.h[1] = __float2bfloat16(v.y);
        p.h[2] = __float2bfloat16(v.z);
        p.h[3] = __float2bfloat16(v.w);
        *(uint2*)&Xb[i] = p.u;
    } else if (b < 12288) {
        int zz = (b - 8192) >> 10;
        int bb = (b - 8192) & 1023;
        int bxt = (bb & 31) * 32, byt = (bb >> 5) * 32;
        const float* W = (zz == 0) ? Wq : (zz == 1) ? Wkv : (zz == 2) ? Wo : Wo0;
        bf16* Wt = (zz == 0) ? WqT : (zz == 1) ? WkvT : (zz == 2) ? WoT : Wo0T;
        int tx = tid & 31, ty = tid >> 5;
        for (int ii = ty; ii < 32; ii += 8)
            tile[ii][tx] = W[(size_t)(byt + ii) * DIM + bxt + tx];
        __syncthreads();
        for (int ii = ty; ii < 32; ii += 8)
            Wt[(size_t)(bxt + ii) * DIM + byt + tx] = __float2bfloat16(tile[tx][ii]);
    } else {
        int idx = (b - 12288) * 256 + tid;
        int t = idx >> 5, ii = idx & 31;
        float freq = 1.0f / powf(10000.0f, (float)(2 * ii) * (1.0f / 64.0f));
        float a = (float)t * freq;
        cosT[idx] = cosf(a);
        sinT[idx] = sinf(a);
    }
}

// --------------- N-FUSED Q+KV projection GEMM (R17, unchanged)
__launch_bounds__(256, 2)
__global__ void k_gemm_qkv(const bf16* __restrict__ A, const bf16* __restrict__ Bq,
                           const bf16* __restrict__ Bkv, const float* __restrict__ cosT,
                           const float* __restrict__ sinT, bf16* __restrict__ Qb,
                           bf16* __restrict__ KVf) {
    __shared__ alignas(16) bf16 SH[36864];        // 72KB: A 3x4096 | B 3x8192 (Bq|Bkv); bounce aliases
    bf16* AsB = SH;                               // [3][4096]
    bf16* BsB = SH + 12288;                       // [3][8192]
    const int K = DIM;
    int tid = threadIdx.x;
    int lane = tid & 63, wave = tid >> 6;
    int hi = lane >> 5, lq = lane & 31;
    int wr = (wave >> 1) * 64, wc = (wave & 1) * 64;
    int id = blockIdx.x;                   // 512 blocks
    int xcd = id & 7, rank = id >> 3;      // rank 0..63
    int by = xcd * 8 + (rank >> 3);        // 0..63
    int n0 = (rank & 7) * 128;
    int m0 = by * 128;
    int row = lane & 15, kk = (lane >> 4) * 8;
    int kkA = kk ^ (((lane >> 1) & 3) << 3);      // T2 read swizzle (row bits 1-2)
    int ch0 = wave * 128 + lane, ch1 = ch0 + 64;
    int r0 = ch0 >> 2, c0e = (ch0 & 3) * 8;
    int r1 = ch1 >> 2, c1e = (ch1 & 3) * 8;
    int c0s = c0e ^ (((r0 >> 1) & 3) << 3);       // T2 pre-swizzled source col
    int c1s = c1e ^ (((r1 >> 1) & 3) << 3);
    f32x4 accQ[4][4] = {};
    f32x4 accK[4][4] = {};

    auto stage = [&](int k0, int b) {
        gload16(&A[(size_t)(m0 + r0) * K + k0 + c0s], &AsB[b * 4096 + wave * 1024]);
        gload16(&A[(size_t)(m0 + r1) * K + k0 + c1s], &AsB[b * 4096 + wave * 1024 + 512]);
        gload16(&Bq[(size_t)(n0 + r0) * K + k0 + c0s], &BsB[b * 8192 + wave * 1024]);
        gload16(&Bq[(size_t)(n0 + r1) * K + k0 + c1s], &BsB[b * 8192 + wave * 1024 + 512]);
        gload16(&Bkv[(size_t)(n0 + r0) * K + k0 + c0s], &BsB[b * 8192 + 4096 + wave * 1024]);
        gload16(&Bkv[(size_t)(n0 + r1) * K + k0 + c1s], &BsB[b * 8192 + 4096 + wave * 1024 + 512]);
    };
    stage(0, 0);
    stage(32, 1);
    asm volatile("s_waitcnt vmcnt(6)" ::: "memory");
    __builtin_amdgcn_s_barrier();
    __builtin_amdgcn_sched_barrier(0);
    int cur = 0;
    for (int k = 0; k < 32; ++k) {
        if (k + 2 < 32) {
            int nb = cur + 2; if (nb >= 3) nb -= 3;
            stage(k * 32 + 64, nb);
        }
        bf16x8 af[4], bq[4], bk[4];
#pragma unroll
        for (int mt = 0; mt < 4; ++mt) af[mt] = *(const bf16x8*)&AsB[cur * 4096 + (wr + mt * 16 + row) * 32 + kkA];
#pragma unroll
        for (int nt = 0; nt < 4; ++nt) bq[nt] = *(const bf16x8*)&BsB[cur * 8192 + (wc + nt * 16 + row) * 32 + kkA];
#pragma unroll
        for (int nt = 0; nt < 4; ++nt) bk[nt] = *(const bf16x8*)&BsB[cur * 8192 + 4096 + (wc + nt * 16 + row) * 32 + kkA];
#pragma unroll
        for (int mt = 0; mt < 4; ++mt)
#pragma unroll
            for (int nt = 0; nt < 4; ++nt) {
                accQ[mt][nt] = __builtin_amdgcn_mfma_f32_16x16x32_bf16(af[mt], bq[nt], accQ[mt][nt], 0, 0, 0);
                accK[mt][nt] = __builtin_amdgcn_mfma_f32_16x16x32_bf16(af[mt], bk[nt], accK[mt][nt], 0, 0, 0);
            }
        if (k + 1 < 32) {
            if (k + 2 < 32) asm volatile("s_waitcnt vmcnt(6)" ::: "memory");
            else            asm volatile("s_waitcnt vmcnt(0)" ::: "memory");
            __builtin_amdgcn_s_barrier();
            __builtin_amdgcn_sched_barrier(0);
        }
        cur = cur + 1; if (cur == 3) cur = 0;
    }
    __syncthreads();   // all LDS reads done before bounce region overwrites staging
    bf16* Tw = SH + wave * (64 * 72);
    int orow = (lane >> 4) * 4, ocol = lane & 15;
    int head_g = (n0 + wc) >> 6;               // 0..15
    int bidx = (m0 + wr) >> 12;
    int tbase = (m0 + wr) & (NSEQ - 1);
    int cch = bidx * NH + head_g;
    // ---- pass 1: Q
#pragma unroll
    for (int mt = 0; mt < 4; ++mt) {
#pragma unroll
        for (int i = 0; i < 4; ++i) {
            int rl = mt * 16 + orow + i;
            int t = tbase + rl;
#pragma unroll
            for (int nt = 0; nt < 2; ++nt) {
                int e = nt * 16 + ocol;
                float x1 = accQ[mt][nt][i], x2 = accQ[mt][nt + 2][i];
                float cv = cosT[t * 32 + e], sv = sinT[t * 32 + e];
                Tw[rl * 72 + e]      = __float2bfloat16((x1 * cv - x2 * sv) * QSCALE);
                Tw[rl * 72 + e + 32] = __float2bfloat16((x2 * cv + x1 * sv) * QSCALE);
            }
        }
    }
    {
        int rsub = lane >> 3, dg = (lane & 7) * 8;
        size_t qbase = ((size_t)cch * NSEQ + tbase) * HD;
#pragma unroll
        for (int rr = 0; rr < 8; ++rr) {
            int rl = rr * 8 + rsub;
            *(uint4*)&Qb[qbase + (size_t)rl * HD + dg] = *(const uint4*)&Tw[rl * 72 + dg];
        }
    }
    // ---- pass 2: KV
#pragma unroll
    for (int mt = 0; mt < 4; ++mt) {
#pragma unroll
        for (int i = 0; i < 4; ++i) {
            int rl = mt * 16 + orow + i;
            int t = tbase + rl;
#pragma unroll
            for (int nt = 0; nt < 2; ++nt) {
                int e = nt * 16 + ocol;
                float x1 = accK[mt][nt][i], x2 = accK[mt][nt + 2][i];
                float cv = cosT[t * 32 + e], sv = sinT[t * 32 + e];
                Tw[rl * 72 + e]      = __float2bfloat16(x1 * cv - x2 * sv);
                Tw[rl * 72 + e + 32] = __float2bfloat16(x2 * cv + x1 * sv);
            }
        }
    }
    {
        size_t kvfbase = ((size_t)cch * 128 + (tbase >> 5)) * 4096;   // elements
#pragma unroll
        for (int st = 0; st < 2; ++st) {
            size_t tb = kvfbase + (size_t)st * 4096;
#pragma unroll
            for (int f = 0; f < 4; ++f)
                *(uint4*)&KVf[tb + f * 512 + lane * 8] =
                    *(const uint4*)&Tw[(st * 32 + lq) * 72 + f * 16 + hi * 8];
#pragma unroll
            for (int m = 0; m < 4; ++m) {
                int d0 = (m >> 1) * 32, sb = m & 1;
                union { bf16 h[8]; uint4 u; } pk;
#pragma unroll
                for (int j = 0; j < 8; ++j)
                    pk.h[j] = Tw[(st * 32 + sb * 16 + hi * 8 + j) * 72 + d0 + lq];
                *(uint4*)&KVf[tb + (size_t)(4 + m) * 512 + lane * 8] = pk.u;
            }
        }
    }
}

// final GEMM: 128x64 tile, 1024 blocks, 3-buffer counted-vmcnt pipeline, T2 swizzle, fp32 out
__launch_bounds__(256, 4)
__global__ void k_gemm_out(const bf16* __restrict__ A, const bf16* __restrict__ Bt0,
                           const bf16* __restrict__ Bt1, const float* __restrict__ bias0,
                           const float* __restrict__ bias1, float* __restrict__ C) {
    __shared__ alignas(16) bf16 As[3][128 * 32];
    __shared__ alignas(16) bf16 Bs[3][64 * 32];
    const int K = DIM;
    int tid = threadIdx.x;
    int lane = tid & 63, wave = tid >> 6;
    int wr = (wave >> 1) * 64, wc = (wave & 1) * 32;
    int id = blockIdx.x;                   // 1024 blocks
    int xcd = id & 7, rank = id >> 3;      // 0..127
    int by = xcd * 8 + (rank >> 4);        // 0..63
    int bx = rank & 15;                    // 0..15
    int m0 = by * 128, n0 = bx * 64;
    bool first = (m0 & (NSEQ - 1)) < MSEG;
    const bf16* Bt = first ? Bt0 : Bt1;
    const float* bias = first ? bias0 : bias1;
    int row = lane & 15, kk = (lane >> 4) * 8;
    int kkA = kk ^ (((lane >> 1) & 3) << 3);
    int ch0 = wave * 128 + lane, ch1 = ch0 + 64;
    int r0 = ch0 >> 2, c0e = (ch0 & 3) * 8;
    int r1 = ch1 >> 2, c1e = (ch1 & 3) * 8;
    int c0s = c0e ^ (((r0 >> 1) & 3) << 3);
    int c1s = c1e ^ (((r1 >> 1) & 3) << 3);
    int cb = wave * 64 + lane;
    int rb = cb >> 2, cbe = (cb & 3) * 8;
    int cbs = cbe ^ (((rb >> 1) & 3) << 3);
    f32x4 acc[4][2] = {};

    auto stage = [&](int k0, int b) {
        gload16(&A[(size_t)(m0 + r0) * K + k0 + c0s], &As[b][wave * 1024]);
        gload16(&A[(size_t)(m0 + r1) * K + k0 + c1s], &As[b][wave * 1024 + 512]);
        gload16(&Bt[(size_t)(n0 + rb) * K + k0 + cbs], &Bs[b][wave * 512]);
    };
    stage(0, 0);
    stage(32, 1);
    asm volatile("s_waitcnt vmcnt(3)" ::: "memory");
    __builtin_amdgcn_s_barrier();
    __builtin_amdgcn_sched_barrier(0);
    int cur = 0;
    for (int k = 0; k < 32; ++k) {
        if (k + 2 < 32) {
            int nb = cur + 2; if (nb >= 3) nb -= 3;
            stage(k * 32 + 64, nb);
        }
        bf16x8 af[4], bfr[2];
#pragma unroll
        for (int mt = 0; mt < 4; ++mt) af[mt] = *(const bf16x8*)&As[cur][(wr + mt * 16 + row) * 32 + kkA];
#pragma unroll
        for (int nt = 0; nt < 2; ++nt) bfr[nt] = *(const bf16x8*)&Bs[cur][(wc + nt * 16 + row) * 32 + kkA];
#pragma unroll
        for (int mt = 0; mt < 4; ++mt)
#pragma unroll
            for (int nt = 0; nt < 2; ++nt)
                acc[mt][nt] = __builtin_amdgcn_mfma_f32_16x16x32_bf16(af[mt], bfr[nt], acc[mt][nt], 0, 0, 0);
        if (k + 1 < 32) {
            if (k + 2 < 32) asm volatile("s_waitcnt vmcnt(3)" ::: "memory");
            else            asm volatile("s_waitcnt vmcnt(0)" ::: "memory");
            __builtin_amdgcn_s_barrier();
            __builtin_amdgcn_sched_barrier(0);
        }
        cur = cur + 1; if (cur == 3) cur = 0;
    }
    int orow = (lane >> 4) * 4, ocol = lane & 15;
#pragma unroll
    for (int mt = 0; mt < 4; ++mt)
#pragma unroll
        for (int nt = 0; nt < 2; ++nt) {
            float bv = bias[n0 + wc + nt * 16 + ocol];
#pragma unroll
            for (int i = 0; i < 4; ++i)
                C[(size_t)(m0 + wr + mt * 16 + orow + i) * DIM + n0 + wc + nt * 16 + ocol] = acc[mt][nt][i] + bv;
        }
}

// ---------------------------------------------------------------- attention (swapped-QK 32x32)
// 2-way in-block KV split + COMPLEMENTARY q-group pairing: wave qsel=0 -> qb=j,
// qsel=1 -> qb=15-j => per-block work constant (49 tiles seg>=1, 17 seg0). Grid 2048.
__launch_bounds__(256, 4)
__global__ void k_attn(const bf16* __restrict__ Qb, const bf16* __restrict__ KVf,
                       bf16* __restrict__ Ob) {
    __shared__ float Osh[2][32][68];
    __shared__ float Msh[4][32];
    __shared__ float Lsh[4][32];
    int lane = threadIdx.x & 63, wave = threadIdx.x >> 6;
    int hi = lane >> 5, lq = lane & 31;
    int half = wave >> 1, qsel = wave & 1;
    int id = blockIdx.x;                        // 2048 blocks
    int xcd = id & 7, rank = id >> 3;           // rank 0..255
    int c = xcd * 4 + (rank & 3);
    int hr = rank >> 2;                         // 0..63
    int j, seg;
    if (hr < 56) { seg = 1 + (hr >> 3); j = hr & 7; }
    else         { seg = 0; j = hr - 56; }
    int qb = qsel ? (15 - j) : j;               // complementary pairing
    int i0 = qb * 32;                           // q-row offset within segment
    int bidx = c >> 4, head = c & 15;
    int tq = seg * MSEG + i0 + lq;
    const bf16* qptr = &Qb[((size_t)c * NSEQ + tq) * HD + hi * 8];
    bf16x8 qf[4];
#pragma unroll
    for (int dc = 0; dc < 4; ++dc) qf[dc] = *(const bf16x8*)&qptr[dc * 16];
    f32x16 o0 = {}, o1 = {};
    float mrun = -FLT_MAX, lrun = 0.f;
    int kvbase = (seg == 0) ? 0 : (seg - 1) * MSEG;
    int cstart = (seg == 0) ? 0 : MSEG;
    int nT = (cstart + i0 + 32) >> 5;           // total 32-kv tiles for this q-group
    int hmid = (nT + 1) >> 1;
    int h0 = half ? hmid : 0;
    int h1 = half ? nT : hmid;

    const bf16* fb = &KVf[((size_t)c * 128 + (kvbase >> 5)) * 4096 + lane * 8];

    for (int it = h0; it < h1; ++it) {
        int c0 = it * 32;
        const bf16* pt = fb + (size_t)it * 4096;
        bf16x8 kf0 = *(const bf16x8*)&pt[0];
        bf16x8 kf1 = *(const bf16x8*)&pt[512];
        bf16x8 kf2 = *(const bf16x8*)&pt[1024];
        bf16x8 kf3 = *(const bf16x8*)&pt[1536];
        f32x16 s = {};
        __builtin_amdgcn_s_setprio(1);
        s = __builtin_amdgcn_mfma_f32_32x32x16_bf16(kf0, qf[0], s, 0, 0, 0);
        s = __builtin_amdgcn_mfma_f32_32x32x16_bf16(kf1, qf[1], s, 0, 0, 0);
        s = __builtin_amdgcn_mfma_f32_32x32x16_bf16(kf2, qf[2], s, 0, 0, 0);
        s = __builtin_amdgcn_mfma_f32_32x32x16_bf16(kf3, qf[3], s, 0, 0, 0);
        __builtin_amdgcn_s_setprio(0);
        bf16x8 vf0 = *(const bf16x8*)&pt[2048];
        bf16x8 vf1 = *(const bf16x8*)&pt[2560];
        bf16x8 vf2 = *(const bf16x8*)&pt[3072];
        bf16x8 vf3 = *(const bf16x8*)&pt[3584];
        if (c0 + 31 >= cstart && c0 + 31 - cstart > i0) {
#pragma unroll
            for (int r = 0; r < 16; ++r) {
                int kvg = c0 + ((r & 3) + 8 * (r >> 2) + 4 * hi);
                if (kvg >= cstart && kvg - cstart > i0 + lq) s[r] = -FLT_MAX;
            }
        }
        float m8[8], m4[4];
#pragma unroll
        for (int r = 0; r < 8; ++r) m8[r] = fmaxf(s[2 * r], s[2 * r + 1]);
#pragma unroll
        for (int r = 0; r < 4; ++r) m4[r] = fmaxf(m8[2 * r], m8[2 * r + 1]);
        float vmax = fmaxf(fmaxf(m4[0], m4[1]), fmaxf(m4[2], m4[3]));
        vmax = fmaxf(vmax, __shfl_xor(vmax, 32));
        if (__any(vmax > mrun + 11.5f)) {
            float nm = fmaxf(mrun, vmax);
            float al = fast_exp2(mrun - nm);
#pragma unroll
            for (int r = 0; r < 16; ++r) { o0[r] *= al; o1[r] *= al; }
            lrun *= al;
            mrun = nm;
        }
        float p[16];
#pragma unroll
        for (int r = 0; r < 16; ++r) p[r] = fast_exp2(s[r] - mrun);
        float a8[8], a4[4];
#pragma unroll
        for (int r = 0; r < 8; ++r) a8[r] = p[2 * r] + p[2 * r + 1];
#pragma unroll
        for (int r = 0; r < 4; ++r) a4[r] = a8[2 * r] + a8[2 * r + 1];
        lrun += (a4[0] + a4[1]) + (a4[2] + a4[3]);
        unsigned pk[8];
#pragma unroll
        for (int k = 0; k < 8; ++k) {
            union { bf16 h[2]; unsigned u; } cv;
            cv.h[0] = __float2bfloat16(p[2 * k]);
            cv.h[1] = __float2bfloat16(p[2 * k + 1]);
            pk[k] = cv.u;
        }
        unsigned u0 = hi ? pk[0] : pk[2];
        unsigned u1 = hi ? pk[1] : pk[3];
        unsigned u2 = hi ? pk[4] : pk[6];
        unsigned u3 = hi ? pk[5] : pk[7];
        unsigned w0 = (unsigned)__shfl_xor((int)u0, 32);
        unsigned w1 = (unsigned)__shfl_xor((int)u1, 32);
        unsigned w2 = (unsigned)__shfl_xor((int)u2, 32);
        unsigned w3 = (unsigned)__shfl_xor((int)u3, 32);
        union { unsigned u[4]; bf16x8 v; } b0, b1;
        b0.u[0] = hi ? w0 : pk[0];
        b0.u[1] = hi ? w1 : pk[1];
        b0.u[2] = hi ? pk[2] : w0;
        b0.u[3] = hi ? pk[3] : w1;
        b1.u[0] = hi ? w2 : pk[4];
        b1.u[1] = hi ? w3 : pk[5];
        b1.u[2] = hi ? pk[6] : w2;
        b1.u[3] = hi ? pk[7] : w3;
        __builtin_amdgcn_s_setprio(1);
        o0 = __builtin_amdgcn_mfma_f32_32x32x16_bf16(vf0, b0.v, o0, 0, 0, 0);
        o1 = __builtin_amdgcn_mfma_f32_32x32x16_bf16(vf2, b0.v, o1, 0, 0, 0);
        o0 = __builtin_amdgcn_mfma_f32_32x32x16_bf16(vf1, b1.v, o0, 0, 0, 0);
        o1 = __builtin_amdgcn_mfma_f32_32x32x16_bf16(vf3, b1.v, o1, 0, 0, 0);
        __builtin_amdgcn_s_setprio(0);
    }
    // ---- 2-partial merge: waves (0,2) share qsel=0, (1,3) share qsel=1
    lrun += __shfl_xor(lrun, 32);
    if (lane < 32) { Msh[wave][lq] = mrun; Lsh[wave][lq] = lrun; }
    __syncthreads();
    float mp = Msh[wave ^ 2][lq];
    float M = fmaxf(mrun, mp);
    float scl = fast_exp2(mrun - M);
    if (half == 0) {
#pragma unroll
        for (int r = 0; r < 16; ++r) {
            int d = (r & 3) + 8 * (r >> 2) + 4 * hi;
            Osh[qsel][lq][d]      = o0[r] * scl;
            Osh[qsel][lq][d + 32] = o1[r] * scl;
        }
    }
    __syncthreads();
    if (half == 1) {
        float lt = lrun * scl + Lsh[wave ^ 2][lq] * fast_exp2(mp - M);
        float inv = 1.0f / lt;
#pragma unroll
        for (int r = 0; r < 16; ++r) {
            int d = (r & 3) + 8 * (r >> 2) + 4 * hi;
            o0[r] = o0[r] * scl + Osh[qsel][lq][d];
            o1[r] = o1[r] * scl + Osh[qsel][lq][d + 32];
        }
        size_t obase = ((size_t)bidx * NSEQ + tq) * DIM + head * HD;
#pragma unroll
        for (int dt = 0; dt < 2; ++dt)
#pragma unroll
            for (int a = 0; a < 4; ++a) {
                union { bf16 h[4]; uint2 u; } pkd;
                const f32x16& ov = dt ? o1 : o0;
#pragma unroll
                for (int i = 0; i < 4; ++i) pkd.h[i] = __float2bfloat16(ov[4 * a + i] * inv);
                *(uint2*)&Ob[obase + dt * 32 + 8 * a + 4 * hi] = pkd.u;
            }
    }
}

// ---------------------------------------------------------------- launch
extern "C" void kernel_launch(void* const* d_in, const int* in_sizes, int n_in,
                              void* d_out, int out_size, void* d_ws, size_t ws_size,
                              hipStream_t stream) {
    const float* x   = (const float*)d_in[0];
    const float* Wq  = (const float*)d_in[1];
    const float* Wkv = (const float*)d_in[2];
    const float* Wo  = (const float*)d_in[3];
    const float* bo  = (const float*)d_in[4];
    const float* Wo0 = (const float*)d_in[5];
    const float* bo0 = (const float*)d_in[6];
    float* out = (float*)d_out;

    char* ws = (char*)d_ws;
    size_t off = 0;
    auto alloc = [&](size_t bytes) { void* p = ws + off; off += (bytes + 255) & ~(size_t)255; return p; };
    float* cosT = (float*)alloc((size_t)NSEQ * 32 * 4);
    float* sinT = (float*)alloc((size_t)NSEQ * 32 * 4);
    bf16* Xb    = (bf16*)alloc((size_t)ROWS * DIM * 2);
    bf16* WqT   = (bf16*)alloc((size_t)DIM * DIM * 2);
    bf16* WkvT  = (bf16*)alloc((size_t)DIM * DIM * 2);
    bf16* WoT   = (bf16*)alloc((size_t)DIM * DIM * 2);
    bf16* Wo0T  = (bf16*)alloc((size_t)DIM * DIM * 2);
    bf16* Qb    = (bf16*)alloc((size_t)NC * NSEQ * HD * 2);
    bf16* KVf   = (bf16*)alloc((size_t)NC * 128 * 4096 * 2);
    bf16* Ob    = (bf16*)alloc((size_t)ROWS * DIM * 2);

    hipLaunchKernelGGL(k_prep, dim3(12800), dim3(256), 0, stream,
                       x, Xb, Wq, Wkv, Wo, Wo0, WqT, WkvT, WoT, Wo0T, cosT, sinT);

    hipLaunchKernelGGL(k_gemm_qkv, dim3(512), dim3(256), 0, stream, Xb, WqT, WkvT, cosT, sinT, Qb, KVf);

    hipLaunchKernelGGL(k_attn, dim3(2048), dim3(256), 0, stream, Qb, KVf, Ob);

    hipLaunchKernelGGL(k_gemm_out, dim3(1024), dim3(256), 0, stream, Ob, Wo0T, WoT, bo0, bo, out);
}

// Round 19
// 133.599 us; speedup vs baseline: 1.0137x; 1.0137x over previous
//
#include <hip/hip_runtime.h>
#include <hip/hip_bf16.h>
#include <float.h>

using bf16 = __hip_bfloat16;
typedef __attribute__((ext_vector_type(8))) short bf16x8;
typedef __attribute__((ext_vector_type(4))) float f32x4;
typedef __attribute__((ext_vector_type(16))) float f32x16;

#define DIM   1024
#define NSEQ  4096
#define BATCH 2
#define NH    16
#define HD    64
#define NSEG  8
#define MSEG  512
#define ROWS  (BATCH*NSEQ)   // 8192
#define NC    (BATCH*NH)     // 32
#define QSCALE (0.125f * 1.44269504f)   // d^-0.5 * log2(e)  (exp2 softmax)

__device__ __forceinline__ float fast_exp2(float x) {
    float r;
    asm volatile("v_exp_f32 %0, %1" : "=v"(r) : "v"(x));
    return r;
}

__device__ __forceinline__ void gload16(const bf16* g, bf16* l) {
    __builtin_amdgcn_global_load_lds((const __attribute__((address_space(1))) unsigned int*)g,
                                     (__attribute__((address_space(3))) unsigned int*)l, 16, 0, 0);
}

// ------------- fused prep: x->bf16 convert | 4x weight transpose | rope table
__global__ void k_prep(const float* __restrict__ x, bf16* __restrict__ Xb,
                       const float* __restrict__ Wq, const float* __restrict__ Wkv,
                       const float* __restrict__ Wo, const float* __restrict__ Wo0,
                       bf16* __restrict__ WqT, bf16* __restrict__ WkvT,
                       bf16* __restrict__ WoT, bf16* __restrict__ Wo0T,
                       float* __restrict__ cosT, float* __restrict__ sinT) {
    __shared__ float tile[32][33];
    int b = blockIdx.x, tid = threadIdx.x;
    if (b < 8192) {
        int i = (b * 256 + tid) * 4;
        float4 v = *(const float4*)&x[i];
        union { bf16 h[4]; uint2 u; } p;
        p.h[0] = __float2bfloat16(v.x);
        p.h[1] = __float2bfloat16(v.y);
        p.h[2] = __float2bfloat16(v.z);
        p.h[3] = __float2bfloat16(v.w);
        *(uint2*)&Xb[i] = p.u;
    } else if (b < 12288) {
        int zz = (b - 8192) >> 10;
        int bb = (b - 8192) & 1023;
        int bxt = (bb & 31) * 32, byt = (bb >> 5) * 32;
        const float* W = (zz == 0) ? Wq : (zz == 1) ? Wkv : (zz == 2) ? Wo : Wo0;
        bf16* Wt = (zz == 0) ? WqT : (zz == 1) ? WkvT : (zz == 2) ? WoT : Wo0T;
        int tx = tid & 31, ty = tid >> 5;
        for (int ii = ty; ii < 32; ii += 8)
            tile[ii][tx] = W[(size_t)(byt + ii) * DIM + bxt + tx];
        __syncthreads();
        for (int ii = ty; ii < 32; ii += 8)
            Wt[(size_t)(bxt + ii) * DIM + byt + tx] = __float2bfloat16(tile[tx][ii]);
    } else {
        int idx = (b - 12288) * 256 + tid;
        int t = idx >> 5, ii = idx & 31;
        float freq = 1.0f / powf(10000.0f, (float)(2 * ii) * (1.0f / 64.0f));
        float a = (float)t * freq;
        cosT[idx] = cosf(a);
        sinT[idx] = sinf(a);
    }
}

// --------------- N-FUSED Q+KV projection GEMM (R17, unchanged)
__launch_bounds__(256, 2)
__global__ void k_gemm_qkv(const bf16* __restrict__ A, const bf16* __restrict__ Bq,
                           const bf16* __restrict__ Bkv, const float* __restrict__ cosT,
                           const float* __restrict__ sinT, bf16* __restrict__ Qb,
                           bf16* __restrict__ KVf) {
    __shared__ alignas(16) bf16 SH[36864];        // 72KB: A 3x4096 | B 3x8192 (Bq|Bkv); bounce aliases
    bf16* AsB = SH;                               // [3][4096]
    bf16* BsB = SH + 12288;                       // [3][8192]
    const int K = DIM;
    int tid = threadIdx.x;
    int lane = tid & 63, wave = tid >> 6;
    int hi = lane >> 5, lq = lane & 31;
    int wr = (wave >> 1) * 64, wc = (wave & 1) * 64;
    int id = blockIdx.x;                   // 512 blocks
    int xcd = id & 7, rank = id >> 3;      // rank 0..63
    int by = xcd * 8 + (rank >> 3);        // 0..63
    int n0 = (rank & 7) * 128;
    int m0 = by * 128;
    int row = lane & 15, kk = (lane >> 4) * 8;
    int kkA = kk ^ (((lane >> 1) & 3) << 3);      // T2 read swizzle (row bits 1-2)
    int ch0 = wave * 128 + lane, ch1 = ch0 + 64;
    int r0 = ch0 >> 2, c0e = (ch0 & 3) * 8;
    int r1 = ch1 >> 2, c1e = (ch1 & 3) * 8;
    int c0s = c0e ^ (((r0 >> 1) & 3) << 3);       // T2 pre-swizzled source col
    int c1s = c1e ^ (((r1 >> 1) & 3) << 3);
    f32x4 accQ[4][4] = {};
    f32x4 accK[4][4] = {};

    auto stage = [&](int k0, int b) {
        gload16(&A[(size_t)(m0 + r0) * K + k0 + c0s], &AsB[b * 4096 + wave * 1024]);
        gload16(&A[(size_t)(m0 + r1) * K + k0 + c1s], &AsB[b * 4096 + wave * 1024 + 512]);
        gload16(&Bq[(size_t)(n0 + r0) * K + k0 + c0s], &BsB[b * 8192 + wave * 1024]);
        gload16(&Bq[(size_t)(n0 + r1) * K + k0 + c1s], &BsB[b * 8192 + wave * 1024 + 512]);
        gload16(&Bkv[(size_t)(n0 + r0) * K + k0 + c0s], &BsB[b * 8192 + 4096 + wave * 1024]);
        gload16(&Bkv[(size_t)(n0 + r1) * K + k0 + c1s], &BsB[b * 8192 + 4096 + wave * 1024 + 512]);
    };
    stage(0, 0);
    stage(32, 1);
    asm volatile("s_waitcnt vmcnt(6)" ::: "memory");
    __builtin_amdgcn_s_barrier();
    __builtin_amdgcn_sched_barrier(0);
    int cur = 0;
    for (int k = 0; k < 32; ++k) {
        if (k + 2 < 32) {
            int nb = cur + 2; if (nb >= 3) nb -= 3;
            stage(k * 32 + 64, nb);
        }
        bf16x8 af[4], bq[4], bk[4];
#pragma unroll
        for (int mt = 0; mt < 4; ++mt) af[mt] = *(const bf16x8*)&AsB[cur * 4096 + (wr + mt * 16 + row) * 32 + kkA];
#pragma unroll
        for (int nt = 0; nt < 4; ++nt) bq[nt] = *(const bf16x8*)&BsB[cur * 8192 + (wc + nt * 16 + row) * 32 + kkA];
#pragma unroll
        for (int nt = 0; nt < 4; ++nt) bk[nt] = *(const bf16x8*)&BsB[cur * 8192 + 4096 + (wc + nt * 16 + row) * 32 + kkA];
#pragma unroll
        for (int mt = 0; mt < 4; ++mt)
#pragma unroll
            for (int nt = 0; nt < 4; ++nt) {
                accQ[mt][nt] = __builtin_amdgcn_mfma_f32_16x16x32_bf16(af[mt], bq[nt], accQ[mt][nt], 0, 0, 0);
                accK[mt][nt] = __builtin_amdgcn_mfma_f32_16x16x32_bf16(af[mt], bk[nt], accK[mt][nt], 0, 0, 0);
            }
        if (k + 1 < 32) {
            if (k + 2 < 32) asm volatile("s_waitcnt vmcnt(6)" ::: "memory");
            else            asm volatile("s_waitcnt vmcnt(0)" ::: "memory");
            __builtin_amdgcn_s_barrier();
            __builtin_amdgcn_sched_barrier(0);
        }
        cur = cur + 1; if (cur == 3) cur = 0;
    }
    __syncthreads();   // all LDS reads done before bounce region overwrites staging
    bf16* Tw = SH + wave * (64 * 72);
    int orow = (lane >> 4) * 4, ocol = lane & 15;
    int head_g = (n0 + wc) >> 6;               // 0..15
    int bidx = (m0 + wr) >> 12;
    int tbase = (m0 + wr) & (NSEQ - 1);
    int cch = bidx * NH + head_g;
    // ---- pass 1: Q
#pragma unroll
    for (int mt = 0; mt < 4; ++mt) {
#pragma unroll
        for (int i = 0; i < 4; ++i) {
            int rl = mt * 16 + orow + i;
            int t = tbase + rl;
#pragma unroll
            for (int nt = 0; nt < 2; ++nt) {
                int e = nt * 16 + ocol;
                float x1 = accQ[mt][nt][i], x2 = accQ[mt][nt + 2][i];
                float cv = cosT[t * 32 + e], sv = sinT[t * 32 + e];
                Tw[rl * 72 + e]      = __float2bfloat16((x1 * cv - x2 * sv) * QSCALE);
                Tw[rl * 72 + e + 32] = __float2bfloat16((x2 * cv + x1 * sv) * QSCALE);
            }
        }
    }
    {
        int rsub = lane >> 3, dg = (lane & 7) * 8;
        size_t qbase = ((size_t)cch * NSEQ + tbase) * HD;
#pragma unroll
        for (int rr = 0; rr < 8; ++rr) {
            int rl = rr * 8 + rsub;
            *(uint4*)&Qb[qbase + (size_t)rl * HD + dg] = *(const uint4*)&Tw[rl * 72 + dg];
        }
    }
    // ---- pass 2: KV
#pragma unroll
    for (int mt = 0; mt < 4; ++mt) {
#pragma unroll
        for (int i = 0; i < 4; ++i) {
            int rl = mt * 16 + orow + i;
            int t = tbase + rl;
#pragma unroll
            for (int nt = 0; nt < 2; ++nt) {
                int e = nt * 16 + ocol;
                float x1 = accK[mt][nt][i], x2 = accK[mt][nt + 2][i];
                float cv = cosT[t * 32 + e], sv = sinT[t * 32 + e];
                Tw[rl * 72 + e]      = __float2bfloat16(x1 * cv - x2 * sv);
                Tw[rl * 72 + e + 32] = __float2bfloat16(x2 * cv + x1 * sv);
            }
        }
    }
    {
        size_t kvfbase = ((size_t)cch * 128 + (tbase >> 5)) * 4096;   // elements
#pragma unroll
        for (int st = 0; st < 2; ++st) {
            size_t tb = kvfbase + (size_t)st * 4096;
#pragma unroll
            for (int f = 0; f < 4; ++f)
                *(uint4*)&KVf[tb + f * 512 + lane * 8] =
                    *(const uint4*)&Tw[(st * 32 + lq) * 72 + f * 16 + hi * 8];
#pragma unroll
            for (int m = 0; m < 4; ++m) {
                int d0 = (m >> 1) * 32, sb = m & 1;
                union { bf16 h[8]; uint4 u; } pk;
#pragma unroll
                for (int j = 0; j < 8; ++j)
                    pk.h[j] = Tw[(st * 32 + sb * 16 + hi * 8 + j) * 72 + d0 + lq];
                *(uint4*)&KVf[tb + (size_t)(4 + m) * 512 + lane * 8] = pk.u;
            }
        }
    }
}

// final GEMM: 128x64 tile, 1024 blocks, 3-buffer counted-vmcnt pipeline, T2 swizzle, fp32 out
__launch_bounds__(256, 4)
__global__ void k_gemm_out(const bf16* __restrict__ A, const bf16* __restrict__ Bt0,
                           const bf16* __restrict__ Bt1, const float* __restrict__ bias0,
                           const float* __restrict__ bias1, float* __restrict__ C) {
    __shared__ alignas(16) bf16 As[3][128 * 32];
    __shared__ alignas(16) bf16 Bs[3][64 * 32];
    const int K = DIM;
    int tid = threadIdx.x;
    int lane = tid & 63, wave = tid >> 6;
    int wr = (wave >> 1) * 64, wc = (wave & 1) * 32;
    int id = blockIdx.x;                   // 1024 blocks
    int xcd = id & 7, rank = id >> 3;      // 0..127
    int by = xcd * 8 + (rank >> 4);        // 0..63
    int bx = rank & 15;                    // 0..15
    int m0 = by * 128, n0 = bx * 64;
    bool first = (m0 & (NSEQ - 1)) < MSEG;
    const bf16* Bt = first ? Bt0 : Bt1;
    const float* bias = first ? bias0 : bias1;
    int row = lane & 15, kk = (lane >> 4) * 8;
    int kkA = kk ^ (((lane >> 1) & 3) << 3);
    int ch0 = wave * 128 + lane, ch1 = ch0 + 64;
    int r0 = ch0 >> 2, c0e = (ch0 & 3) * 8;
    int r1 = ch1 >> 2, c1e = (ch1 & 3) * 8;
    int c0s = c0e ^ (((r0 >> 1) & 3) << 3);
    int c1s = c1e ^ (((r1 >> 1) & 3) << 3);
    int cb = wave * 64 + lane;
    int rb = cb >> 2, cbe = (cb & 3) * 8;
    int cbs = cbe ^ (((rb >> 1) & 3) << 3);
    f32x4 acc[4][2] = {};

    auto stage = [&](int k0, int b) {
        gload16(&A[(size_t)(m0 + r0) * K + k0 + c0s], &As[b][wave * 1024]);
        gload16(&A[(size_t)(m0 + r1) * K + k0 + c1s], &As[b][wave * 1024 + 512]);
        gload16(&Bt[(size_t)(n0 + rb) * K + k0 + cbs], &Bs[b][wave * 512]);
    };
    stage(0, 0);
    stage(32, 1);
    asm volatile("s_waitcnt vmcnt(3)" ::: "memory");
    __builtin_amdgcn_s_barrier();
    __builtin_amdgcn_sched_barrier(0);
    int cur = 0;
    for (int k = 0; k < 32; ++k) {
        if (k + 2 < 32) {
            int nb = cur + 2; if (nb >= 3) nb -= 3;
            stage(k * 32 + 64, nb);
        }
        bf16x8 af[4], bfr[2];
#pragma unroll
        for (int mt = 0; mt < 4; ++mt) af[mt] = *(const bf16x8*)&As[cur][(wr + mt * 16 + row) * 32 + kkA];
#pragma unroll
        for (int nt = 0; nt < 2; ++nt) bfr[nt] = *(const bf16x8*)&Bs[cur][(wc + nt * 16 + row) * 32 + kkA];
#pragma unroll
        for (int mt = 0; mt < 4; ++mt)
#pragma unroll
            for (int nt = 0; nt < 2; ++nt)
                acc[mt][nt] = __builtin_amdgcn_mfma_f32_16x16x32_bf16(af[mt], bfr[nt], acc[mt][nt], 0, 0, 0);
        if (k + 1 < 32) {
            if (k + 2 < 32) asm volatile("s_waitcnt vmcnt(3)" ::: "memory");
            else            asm volatile("s_waitcnt vmcnt(0)" ::: "memory");
            __builtin_amdgcn_s_barrier();
            __builtin_amdgcn_sched_barrier(0);
        }
        cur = cur + 1; if (cur == 3) cur = 0;
    }
    int orow = (lane >> 4) * 4, ocol = lane & 15;
#pragma unroll
    for (int mt = 0; mt < 4; ++mt)
#pragma unroll
        for (int nt = 0; nt < 2; ++nt) {
            float bv = bias[n0 + wc + nt * 16 + ocol];
#pragma unroll
            for (int i = 0; i < 4; ++i)
                C[(size_t)(m0 + wr + mt * 16 + orow + i) * DIM + n0 + wc + nt * 16 + ocol] = acc[mt][nt][i] + bv;
        }
}

// ---------------------------------------------------------------- attention (swapped-QK 32x32)
// 2-way in-block KV split; R17 adjacent q-group pairing (qb = 2j+qsel). Grid 2048.
__launch_bounds__(256, 4)
__global__ void k_attn(const bf16* __restrict__ Qb, const bf16* __restrict__ KVf,
                       bf16* __restrict__ Ob) {
    __shared__ float Osh[2][32][68];
    __shared__ float Msh[4][32];
    __shared__ float Lsh[4][32];
    int lane = threadIdx.x & 63, wave = threadIdx.x >> 6;
    int hi = lane >> 5, lq = lane & 31;
    int half = wave >> 1, qsel = wave & 1;
    int id = blockIdx.x;                        // 2048 blocks
    int xcd = id & 7, rank = id >> 3;           // rank 0..255
    int c = xcd * 4 + (rank & 3);
    int hr = rank >> 2;                         // 0..63, heavy-first
    int j, seg;
    if (hr < 56) { j = 7 - hr / 7; seg = 1 + hr % 7; }
    else         { seg = 0; j = 63 - hr; }
    int qb = 2 * j + qsel;
    int i0 = qb * 32;                           // q-row offset within segment
    int bidx = c >> 4, head = c & 15;
    int tq = seg * MSEG + i0 + lq;
    const bf16* qptr = &Qb[((size_t)c * NSEQ + tq) * HD + hi * 8];
    bf16x8 qf[4];
#pragma unroll
    for (int dc = 0; dc < 4; ++dc) qf[dc] = *(const bf16x8*)&qptr[dc * 16];
    f32x16 o0 = {}, o1 = {};
    float mrun = -FLT_MAX, lrun = 0.f;
    int kvbase = (seg == 0) ? 0 : (seg - 1) * MSEG;
    int cstart = (seg == 0) ? 0 : MSEG;
    int nT = (cstart + i0 + 32) >> 5;           // total 32-kv tiles for this q-group
    int hmid = (nT + 1) >> 1;
    int h0 = half ? hmid : 0;
    int h1 = half ? nT : hmid;

    const bf16* fb = &KVf[((size_t)c * 128 + (kvbase >> 5)) * 4096 + lane * 8];

    for (int it = h0; it < h1; ++it) {
        int c0 = it * 32;
        const bf16* pt = fb + (size_t)it * 4096;
        bf16x8 kf0 = *(const bf16x8*)&pt[0];
        bf16x8 kf1 = *(const bf16x8*)&pt[512];
        bf16x8 kf2 = *(const bf16x8*)&pt[1024];
        bf16x8 kf3 = *(const bf16x8*)&pt[1536];
        f32x16 s = {};
        __builtin_amdgcn_s_setprio(1);
        s = __builtin_amdgcn_mfma_f32_32x32x16_bf16(kf0, qf[0], s, 0, 0, 0);
        s = __builtin_amdgcn_mfma_f32_32x32x16_bf16(kf1, qf[1], s, 0, 0, 0);
        s = __builtin_amdgcn_mfma_f32_32x32x16_bf16(kf2, qf[2], s, 0, 0, 0);
        s = __builtin_amdgcn_mfma_f32_32x32x16_bf16(kf3, qf[3], s, 0, 0, 0);
        __builtin_amdgcn_s_setprio(0);
        bf16x8 vf0 = *(const bf16x8*)&pt[2048];
        bf16x8 vf1 = *(const bf16x8*)&pt[2560];
        bf16x8 vf2 = *(const bf16x8*)&pt[3072];
        bf16x8 vf3 = *(const bf16x8*)&pt[3584];
        if (c0 + 31 >= cstart && c0 + 31 - cstart > i0) {
#pragma unroll
            for (int r = 0; r < 16; ++r) {
                int kvg = c0 + ((r & 3) + 8 * (r >> 2) + 4 * hi);
                if (kvg >= cstart && kvg - cstart > i0 + lq) s[r] = -FLT_MAX;
            }
        }
        float m8[8], m4[4];
#pragma unroll
        for (int r = 0; r < 8; ++r) m8[r] = fmaxf(s[2 * r], s[2 * r + 1]);
#pragma unroll
        for (int r = 0; r < 4; ++r) m4[r] = fmaxf(m8[2 * r], m8[2 * r + 1]);
        float vmax = fmaxf(fmaxf(m4[0], m4[1]), fmaxf(m4[2], m4[3]));
        vmax = fmaxf(vmax, __shfl_xor(vmax, 32));
        if (__any(vmax > mrun + 11.5f)) {
            float nm = fmaxf(mrun, vmax);
            float al = fast_exp2(mrun - nm);
#pragma unroll
            for (int r = 0; r < 16; ++r) { o0[r] *= al; o1[r] *= al; }
            lrun *= al;
            mrun = nm;
        }
        float p[16];
#pragma unroll
        for (int r = 0; r < 16; ++r) p[r] = fast_exp2(s[r] - mrun);
        float a8[8], a4[4];
#pragma unroll
        for (int r = 0; r < 8; ++r) a8[r] = p[2 * r] + p[2 * r + 1];
#pragma unroll
        for (int r = 0; r < 4; ++r) a4[r] = a8[2 * r] + a8[2 * r + 1];
        lrun += (a4[0] + a4[1]) + (a4[2] + a4[3]);
        unsigned pk[8];
#pragma unroll
        for (int k = 0; k < 8; ++k) {
            union { bf16 h[2]; unsigned u; } cv;
            cv.h[0] = __float2bfloat16(p[2 * k]);
            cv.h[1] = __float2bfloat16(p[2 * k + 1]);
            pk[k] = cv.u;
        }
        unsigned u0 = hi ? pk[0] : pk[2];
        unsigned u1 = hi ? pk[1] : pk[3];
        unsigned u2 = hi ? pk[4] : pk[6];
        unsigned u3 = hi ? pk[5] : pk[7];
        unsigned w0 = (unsigned)__shfl_xor((int)u0, 32);
        unsigned w1 = (unsigned)__shfl_xor((int)u1, 32);
        unsigned w2 = (unsigned)__shfl_xor((int)u2, 32);
        unsigned w3 = (unsigned)__shfl_xor((int)u3, 32);
        union { unsigned u[4]; bf16x8 v; } b0, b1;
        b0.u[0] = hi ? w0 : pk[0];
        b0.u[1] = hi ? w1 : pk[1];
        b0.u[2] = hi ? pk[2] : w0;
        b0.u[3] = hi ? pk[3] : w1;
        b1.u[0] = hi ? w2 : pk[4];
        b1.u[1] = hi ? w3 : pk[5];
        b1.u[2] = hi ? pk[6] : w2;
        b1.u[3] = hi ? pk[7] : w3;
        __builtin_amdgcn_s_setprio(1);
        o0 = __builtin_amdgcn_mfma_f32_32x32x16_bf16(vf0, b0.v, o0, 0, 0, 0);
        o1 = __builtin_amdgcn_mfma_f32_32x32x16_bf16(vf2, b0.v, o1, 0, 0, 0);
        o0 = __builtin_amdgcn_mfma_f32_32x32x16_bf16(vf1, b1.v, o0, 0, 0, 0);
        o1 = __builtin_amdgcn_mfma_f32_32x32x16_bf16(vf3, b1.v, o1, 0, 0, 0);
        __builtin_amdgcn_s_setprio(0);
    }
    // ---- 2-partial merge: waves (0,2) share qsel=0, (1,3) share qsel=1
    lrun += __shfl_xor(lrun, 32);
    if (lane < 32) { Msh[wave][lq] = mrun; Lsh[wave][lq] = lrun; }
    __syncthreads();
    float mp = Msh[wave ^ 2][lq];
    float M = fmaxf(mrun, mp);
    float scl = fast_exp2(mrun - M);
    if (half == 0) {
#pragma unroll
        for (int r = 0; r < 16; ++r) {
            int d = (r & 3) + 8 * (r >> 2) + 4 * hi;
            Osh[qsel][lq][d]      = o0[r] * scl;
            Osh[qsel][lq][d + 32] = o1[r] * scl;
        }
    }
    __syncthreads();
    if (half == 1) {
        float lt = lrun * scl + Lsh[wave ^ 2][lq] * fast_exp2(mp - M);
        float inv = 1.0f / lt;
#pragma unroll
        for (int r = 0; r < 16; ++r) {
            int d = (r & 3) + 8 * (r >> 2) + 4 * hi;
            o0[r] = o0[r] * scl + Osh[qsel][lq][d];
            o1[r] = o1[r] * scl + Osh[qsel][lq][d + 32];
        }
        size_t obase = ((size_t)bidx * NSEQ + tq) * DIM + head * HD;
#pragma unroll
        for (int dt = 0; dt < 2; ++dt)
#pragma unroll
            for (int a = 0; a < 4; ++a) {
                union { bf16 h[4]; uint2 u; } pkd;
                const f32x16& ov = dt ? o1 : o0;
#pragma unroll
                for (int i = 0; i < 4; ++i) pkd.h[i] = __float2bfloat16(ov[4 * a + i] * inv);
                *(uint2*)&Ob[obase + dt * 32 + 8 * a + 4 * hi] = pkd.u;
            }
    }
}

// ---------------------------------------------------------------- launch
extern "C" void kernel_launch(void* const* d_in, const int* in_sizes, int n_in,
                              void* d_out, int out_size, void* d_ws, size_t ws_size,
                              hipStream_t stream) {
    const float* x   = (const float*)d_in[0];
    const float* Wq  = (const float*)d_in[1];
    const float* Wkv = (const float*)d_in[2];
    const float* Wo  = (const float*)d_in[3];
    const float* bo  = (const float*)d_in[4];
    const float* Wo0 = (const float*)d_in[5];
    const float* bo0 = (const float*)d_in[6];
    float* out = (float*)d_out;

    char* ws = (char*)d_ws;
    size_t off = 0;
    auto alloc = [&](size_t bytes) { void* p = ws + off; off += (bytes + 255) & ~(size_t)255; return p; };
    float* cosT = (float*)alloc((size_t)NSEQ * 32 * 4);
    float* sinT = (float*)alloc((size_t)NSEQ * 32 * 4);
    bf16* Xb    = (bf16*)alloc((size_t)ROWS * DIM * 2);
    bf16* WqT   = (bf16*)alloc((size_t)DIM * DIM * 2);
    bf16* WkvT  = (bf16*)alloc((size_t)DIM * DIM * 2);
    bf16* WoT   = (bf16*)alloc((size_t)DIM * DIM * 2);
    bf16* Wo0T  = (bf16*)alloc((size_t)DIM * DIM * 2);
    bf16* Qb    = (bf16*)alloc((size_t)NC * NSEQ * HD * 2);
    bf16* KVf   = (bf16*)alloc((size_t)NC * 128 * 4096 * 2);
    bf16* Ob    = (bf16*)alloc((size_t)ROWS * DIM * 2);

    hipLaunchKernelGGL(k_prep, dim3(12800), dim3(256), 0, stream,
                       x, Xb, Wq, Wkv, Wo, Wo0, WqT, WkvT, WoT, Wo0T, cosT, sinT);

    hipLaunchKernelGGL(k_gemm_qkv, dim3(512), dim3(256), 0, stream, Xb, WqT, WkvT, cosT, sinT, Qb, KVf);

    hipLaunchKernelGGL(k_attn, dim3(2048), dim3(256), 0, stream, Qb, KVf, Ob);

    hipLaunchKernelGGL(k_gemm_out, dim3(1024), dim3(256), 0, stream, Ob, Wo0T, WoT, bo0, bo, out);
}

// Round 21
// 133.360 us; speedup vs baseline: 1.0155x; 1.0018x over previous
//
#include <hip/hip_runtime.h>
#include <hip/hip_bf16.h>
#include <float.h>

using bf16 = __hip_bfloat16;
typedef __attribute__((ext_vector_type(8))) short bf16x8;
typedef __attribute__((ext_vector_type(4))) float f32x4;
typedef __attribute__((ext_vector_type(16))) float f32x16;

#define DIM   1024
#define NSEQ  4096
#define BATCH 2
#define NH    16
#define HD    64
#define NSEG  8
#define MSEG  512
#define ROWS  (BATCH*NSEQ)   // 8192
#define NC    (BATCH*NH)     // 32
#define QSCALE (0.125f * 1.44269504f)   // d^-0.5 * log2(e)  (exp2 softmax)

__device__ __forceinline__ float fast_exp2(float x) {
    float r;
    asm volatile("v_exp_f32 %0, %1" : "=v"(r) : "v"(x));
    return r;
}

__device__ __forceinline__ void gload16(const bf16* g, bf16* l) {
    __builtin_amdgcn_global_load_lds((const __attribute__((address_space(1))) unsigned int*)g,
                                     (__attribute__((address_space(3))) unsigned int*)l, 16, 0, 0);
}

// ------------- fused prep: x->bf16 convert | 4x weight transpose | rope table
__global__ void k_prep(const float* __restrict__ x, bf16* __restrict__ Xb,
                       const float* __restrict__ Wq, const float* __restrict__ Wkv,
                       const float* __restrict__ Wo, const float* __restrict__ Wo0,
                       bf16* __restrict__ WqT, bf16* __restrict__ WkvT,
                       bf16* __restrict__ WoT, bf16* __restrict__ Wo0T,
                       float* __restrict__ cosT, float* __restrict__ sinT) {
    __shared__ float tile[32][33];
    int b = blockIdx.x, tid = threadIdx.x;
    if (b < 8192) {
        int i = (b * 256 + tid) * 4;
        float4 v = *(const float4*)&x[i];
        union { bf16 h[4]; uint2 u; } p;
        p.h[0] = __float2bfloat16(v.x);
        p.h[1] = __float2bfloat16(v.y);
        p.h[2] = __float2bfloat16(v.z);
        p.h[3] = __float2bfloat16(v.w);
        *(uint2*)&Xb[i] = p.u;
    } else if (b < 12288) {
        int zz = (b - 8192) >> 10;
        int bb = (b - 8192) & 1023;
        int bxt = (bb & 31) * 32, byt = (bb >> 5) * 32;
        const float* W = (zz == 0) ? Wq : (zz == 1) ? Wkv : (zz == 2) ? Wo : Wo0;
        bf16* Wt = (zz == 0) ? WqT : (zz == 1) ? WkvT : (zz == 2) ? WoT : Wo0T;
        int tx = tid & 31, ty = tid >> 5;
        for (int ii = ty; ii < 32; ii += 8)
            tile[ii][tx] = W[(size_t)(byt + ii) * DIM + bxt + tx];
        __syncthreads();
        for (int ii = ty; ii < 32; ii += 8)
            Wt[(size_t)(bxt + ii) * DIM + byt + tx] = __float2bfloat16(tile[tx][ii]);
    } else {
        int idx = (b - 12288) * 256 + tid;
        int t = idx >> 5, ii = idx & 31;
        float freq = 1.0f / powf(10000.0f, (float)(2 * ii) * (1.0f / 64.0f));
        float a = (float)t * freq;
        cosT[idx] = cosf(a);
        sinT[idx] = sinf(a);
    }
}

// --------------- N-FUSED Q+KV projection GEMM
__launch_bounds__(256, 2)
__global__ void k_gemm_qkv(const bf16* __restrict__ A, const bf16* __restrict__ Bq,
                           const bf16* __restrict__ Bkv, const float* __restrict__ cosT,
                           const float* __restrict__ sinT, bf16* __restrict__ Qb,
                           bf16* __restrict__ KVf) {
    __shared__ alignas(16) bf16 SH[36864];        // 72KB: A 3x4096 | B 3x8192 (Bq|Bkv); bounce aliases
    bf16* AsB = SH;                               // [3][4096]
    bf16* BsB = SH + 12288;                       // [3][8192]
    const int K = DIM;
    int tid = threadIdx.x;
    int lane = tid & 63, wave = tid >> 6;
    int hi = lane >> 5, lq = lane & 31;
    int wr = (wave >> 1) * 64, wc = (wave & 1) * 64;
    int id = blockIdx.x;                   // 512 blocks
    int xcd = id & 7, rank = id >> 3;      // rank 0..63
    int by = xcd * 8 + (rank >> 3);        // 0..63
    int n0 = (rank & 7) * 128;
    int m0 = by * 128;
    int row = lane & 15, kk = (lane >> 4) * 8;
    int kkA = kk ^ (((lane >> 1) & 3) << 3);      // T2 read swizzle (row bits 1-2)
    int ch0 = wave * 128 + lane, ch1 = ch0 + 64;
    int r0 = ch0 >> 2, c0e = (ch0 & 3) * 8;
    int r1 = ch1 >> 2, c1e = (ch1 & 3) * 8;
    int c0s = c0e ^ (((r0 >> 1) & 3) << 3);       // T2 pre-swizzled source col
    int c1s = c1e ^ (((r1 >> 1) & 3) << 3);
    f32x4 accQ[4][4] = {};
    f32x4 accK[4][4] = {};

    auto stage = [&](int k0, int b) {
        gload16(&A[(size_t)(m0 + r0) * K + k0 + c0s], &AsB[b * 4096 + wave * 1024]);
        gload16(&A[(size_t)(m0 + r1) * K + k0 + c1s], &AsB[b * 4096 + wave * 1024 + 512]);
        gload16(&Bq[(size_t)(n0 + r0) * K + k0 + c0s], &BsB[b * 8192 + wave * 1024]);
        gload16(&Bq[(size_t)(n0 + r1) * K + k0 + c1s], &BsB[b * 8192 + wave * 1024 + 512]);
        gload16(&Bkv[(size_t)(n0 + r0) * K + k0 + c0s], &BsB[b * 8192 + 4096 + wave * 1024]);
        gload16(&Bkv[(size_t)(n0 + r1) * K + k0 + c1s], &BsB[b * 8192 + 4096 + wave * 1024 + 512]);
    };
    stage(0, 0);
    stage(32, 1);
    asm volatile("s_waitcnt vmcnt(6)" ::: "memory");
    __builtin_amdgcn_s_barrier();
    __builtin_amdgcn_sched_barrier(0);
    int cur = 0;
    for (int k = 0; k < 32; ++k) {
        if (k + 2 < 32) {
            int nb = cur + 2; if (nb >= 3) nb -= 3;
            stage(k * 32 + 64, nb);
        }
        bf16x8 af[4], bq[4], bk[4];
#pragma unroll
        for (int mt = 0; mt < 4; ++mt) af[mt] = *(const bf16x8*)&AsB[cur * 4096 + (wr + mt * 16 + row) * 32 + kkA];
#pragma unroll
        for (int nt = 0; nt < 4; ++nt) bq[nt] = *(const bf16x8*)&BsB[cur * 8192 + (wc + nt * 16 + row) * 32 + kkA];
#pragma unroll
        for (int nt = 0; nt < 4; ++nt) bk[nt] = *(const bf16x8*)&BsB[cur * 8192 + 4096 + (wc + nt * 16 + row) * 32 + kkA];
#pragma unroll
        for (int mt = 0; mt < 4; ++mt)
#pragma unroll
            for (int nt = 0; nt < 4; ++nt) {
                accQ[mt][nt] = __builtin_amdgcn_mfma_f32_16x16x32_bf16(af[mt], bq[nt], accQ[mt][nt], 0, 0, 0);
                accK[mt][nt] = __builtin_amdgcn_mfma_f32_16x16x32_bf16(af[mt], bk[nt], accK[mt][nt], 0, 0, 0);
            }
        if (k + 1 < 32) {
            if (k + 2 < 32) asm volatile("s_waitcnt vmcnt(6)" ::: "memory");
            else            asm volatile("s_waitcnt vmcnt(0)" ::: "memory");
            __builtin_amdgcn_s_barrier();
            __builtin_amdgcn_sched_barrier(0);
        }
        cur = cur + 1; if (cur == 3) cur = 0;
    }
    __syncthreads();   // all LDS reads done before bounce region overwrites staging
    bf16* Tw = SH + wave * (64 * 72);
    int orow = (lane >> 4) * 4, ocol = lane & 15;
    int head_g = (n0 + wc) >> 6;               // 0..15
    int bidx = (m0 + wr) >> 12;
    int tbase = (m0 + wr) & (NSEQ - 1);
    int cch = bidx * NH + head_g;
    // ---- pass 1: Q
#pragma unroll
    for (int mt = 0; mt < 4; ++mt) {
#pragma unroll
        for (int i = 0; i < 4; ++i) {
            int rl = mt * 16 + orow + i;
            int t = tbase + rl;
#pragma unroll
            for (int nt = 0; nt < 2; ++nt) {
                int e = nt * 16 + ocol;
                float x1 = accQ[mt][nt][i], x2 = accQ[mt][nt + 2][i];
                float cv = cosT[t * 32 + e], sv = sinT[t * 32 + e];
                Tw[rl * 72 + e]      = __float2bfloat16((x1 * cv - x2 * sv) * QSCALE);
                Tw[rl * 72 + e + 32] = __float2bfloat16((x2 * cv + x1 * sv) * QSCALE);
            }
        }
    }
    {
        int rsub = lane >> 3, dg = (lane & 7) * 8;
        size_t qbase = ((size_t)cch * NSEQ + tbase) * HD;
#pragma unroll
        for (int rr = 0; rr < 8; ++rr) {
            int rl = rr * 8 + rsub;
            *(uint4*)&Qb[qbase + (size_t)rl * HD + dg] = *(const uint4*)&Tw[rl * 72 + dg];
        }
    }
    // ---- pass 2: KV
#pragma unroll
    for (int mt = 0; mt < 4; ++mt) {
#pragma unroll
        for (int i = 0; i < 4; ++i) {
            int rl = mt * 16 + orow + i;
            int t = tbase + rl;
#pragma unroll
            for (int nt = 0; nt < 2; ++nt) {
                int e = nt * 16 + ocol;
                float x1 = accK[mt][nt][i], x2 = accK[mt][nt + 2][i];
                float cv = cosT[t * 32 + e], sv = sinT[t * 32 + e];
                Tw[rl * 72 + e]      = __float2bfloat16(x1 * cv - x2 * sv);
                Tw[rl * 72 + e + 32] = __float2bfloat16(x2 * cv + x1 * sv);
            }
        }
    }
    {
        size_t kvfbase = ((size_t)cch * 128 + (tbase >> 5)) * 4096;   // elements
#pragma unroll
        for (int st = 0; st < 2; ++st) {
            size_t tb = kvfbase + (size_t)st * 4096;
#pragma unroll
            for (int f = 0; f < 4; ++f)
                *(uint4*)&KVf[tb + f * 512 + lane * 8] =
                    *(const uint4*)&Tw[(st * 32 + lq) * 72 + f * 16 + hi * 8];
#pragma unroll
            for (int m = 0; m < 4; ++m) {
                int d0 = (m >> 1) * 32, sb = m & 1;
                union { bf16 h[8]; uint4 u; } pk;
#pragma unroll
                for (int j = 0; j < 8; ++j)
                    pk.h[j] = Tw[(st * 32 + sb * 16 + hi * 8 + j) * 72 + d0 + lq];
                *(uint4*)&KVf[tb + (size_t)(4 + m) * 512 + lane * 8] = pk.u;
            }
        }
    }
}

// final GEMM: 128x64 tile, 1024 blocks, 3-buffer counted-vmcnt pipeline, T2 swizzle, fp32 out
__launch_bounds__(256, 4)
__global__ void k_gemm_out(const bf16* __restrict__ A, const bf16* __restrict__ Bt0,
                           const bf16* __restrict__ Bt1, const float* __restrict__ bias0,
                           const float* __restrict__ bias1, float* __restrict__ C) {
    __shared__ alignas(16) bf16 As[3][128 * 32];
    __shared__ alignas(16) bf16 Bs[3][64 * 32];
    const int K = DIM;
    int tid = threadIdx.x;
    int lane = tid & 63, wave = tid >> 6;
    int wr = (wave >> 1) * 64, wc = (wave & 1) * 32;
    int id = blockIdx.x;                   // 1024 blocks
    int xcd = id & 7, rank = id >> 3;      // 0..127
    int by = xcd * 8 + (rank >> 4);        // 0..63
    int bx = rank & 15;                    // 0..15
    int m0 = by * 128, n0 = bx * 64;
    bool first = (m0 & (NSEQ - 1)) < MSEG;
    const bf16* Bt = first ? Bt0 : Bt1;
    const float* bias = first ? bias0 : bias1;
    int row = lane & 15, kk = (lane >> 4) * 8;
    int kkA = kk ^ (((lane >> 1) & 3) << 3);
    int ch0 = wave * 128 + lane, ch1 = ch0 + 64;
    int r0 = ch0 >> 2, c0e = (ch0 & 3) * 8;
    int r1 = ch1 >> 2, c1e = (ch1 & 3) * 8;
    int c0s = c0e ^ (((r0 >> 1) & 3) << 3);
    int c1s = c1e ^ (((r1 >> 1) & 3) << 3);
    int cb = wave * 64 + lane;
    int rb = cb >> 2, cbe = (cb & 3) * 8;
    int cbs = cbe ^ (((rb >> 1) & 3) << 3);
    f32x4 acc[4][2] = {};

    auto stage = [&](int k0, int b) {
        gload16(&A[(size_t)(m0 + r0) * K + k0 + c0s], &As[b][wave * 1024]);
        gload16(&A[(size_t)(m0 + r1) * K + k0 + c1s], &As[b][wave * 1024 + 512]);
        gload16(&Bt[(size_t)(n0 + rb) * K + k0 + cbs], &Bs[b][wave * 512]);
    };
    stage(0, 0);
    stage(32, 1);
    asm volatile("s_waitcnt vmcnt(3)" ::: "memory");
    __builtin_amdgcn_s_barrier();
    __builtin_amdgcn_sched_barrier(0);
    int cur = 0;
    for (int k = 0; k < 32; ++k) {
        if (k + 2 < 32) {
            int nb = cur + 2; if (nb >= 3) nb -= 3;
            stage(k * 32 + 64, nb);
        }
        bf16x8 af[4], bfr[2];
#pragma unroll
        for (int mt = 0; mt < 4; ++mt) af[mt] = *(const bf16x8*)&As[cur][(wr + mt * 16 + row) * 32 + kkA];
#pragma unroll
        for (int nt = 0; nt < 2; ++nt) bfr[nt] = *(const bf16x8*)&Bs[cur][(wc + nt * 16 + row) * 32 + kkA];
#pragma unroll
        for (int mt = 0; mt < 4; ++mt)
#pragma unroll
            for (int nt = 0; nt < 2; ++nt)
                acc[mt][nt] = __builtin_amdgcn_mfma_f32_16x16x32_bf16(af[mt], bfr[nt], acc[mt][nt], 0, 0, 0);
        if (k + 1 < 32) {
            if (k + 2 < 32) asm volatile("s_waitcnt vmcnt(3)" ::: "memory");
            else            asm volatile("s_waitcnt vmcnt(0)" ::: "memory");
            __builtin_amdgcn_s_barrier();
            __builtin_amdgcn_sched_barrier(0);
        }
        cur = cur + 1; if (cur == 3) cur = 0;
    }
    int orow = (lane >> 4) * 4, ocol = lane & 15;
#pragma unroll
    for (int mt = 0; mt < 4; ++mt)
#pragma unroll
        for (int nt = 0; nt < 2; ++nt) {
            float bv = bias[n0 + wc + nt * 16 + ocol];
#pragma unroll
            for (int i = 0; i < 4; ++i)
                C[(size_t)(m0 + wr + mt * 16 + orow + i) * DIM + n0 + wc + nt * 16 + ocol] = acc[mt][nt][i] + bv;
        }
}

// ---------------------------------------------------------------- attention (swapped-QK 32x32)
// 2-way in-block KV split; adjacent q-group pairing (qb = 2j+qsel). Grid 2048. (R19 verified)
__launch_bounds__(256, 4)
__global__ void k_attn(const bf16* __restrict__ Qb, const bf16* __restrict__ KVf,
                       bf16* __restrict__ Ob) {
    __shared__ float Osh[2][32][68];
    __shared__ float Msh[4][32];
    __shared__ float Lsh[4][32];
    int lane = threadIdx.x & 63, wave = threadIdx.x >> 6;
    int hi = lane >> 5, lq = lane & 31;
    int half = wave >> 1, qsel = wave & 1;
    int id = blockIdx.x;                        // 2048 blocks
    int xcd = id & 7, rank = id >> 3;           // rank 0..255
    int c = xcd * 4 + (rank & 3);
    int hr = rank >> 2;                         // 0..63, heavy-first
    int j, seg;
    if (hr < 56) { j = 7 - hr / 7; seg = 1 + hr % 7; }
    else         { seg = 0; j = 63 - hr; }
    int qb = 2 * j + qsel;
    int i0 = qb * 32;                           // q-row offset within segment
    int bidx = c >> 4, head = c & 15;
    int tq = seg * MSEG + i0 + lq;
    const bf16* qptr = &Qb[((size_t)c * NSEQ + tq) * HD + hi * 8];
    bf16x8 qf[4];
#pragma unroll
    for (int dc = 0; dc < 4; ++dc) qf[dc] = *(const bf16x8*)&qptr[dc * 16];
    f32x16 o0 = {}, o1 = {};
    float mrun = -FLT_MAX, lrun = 0.f;
    int kvbase = (seg == 0) ? 0 : (seg - 1) * MSEG;
    int cstart = (seg == 0) ? 0 : MSEG;
    int nT = (cstart + i0 + 32) >> 5;           // total 32-kv tiles for this q-group
    int hmid = (nT + 1) >> 1;
    int h0 = half ? hmid : 0;
    int h1 = half ? nT : hmid;

    const bf16* fb = &KVf[((size_t)c * 128 + (kvbase >> 5)) * 4096 + lane * 8];

    for (int it = h0; it < h1; ++it) {
        int c0 = it * 32;
        const bf16* pt = fb + (size_t)it * 4096;
        bf16x8 kf0 = *(const bf16x8*)&pt[0];
        bf16x8 kf1 = *(const bf16x8*)&pt[512];
        bf16x8 kf2 = *(const bf16x8*)&pt[1024];
        bf16x8 kf3 = *(const bf16x8*)&pt[1536];
        f32x16 s = {};
        __builtin_amdgcn_s_setprio(1);
        s = __builtin_amdgcn_mfma_f32_32x32x16_bf16(kf0, qf[0], s, 0, 0, 0);
        s = __builtin_amdgcn_mfma_f32_32x32x16_bf16(kf1, qf[1], s, 0, 0, 0);
        s = __builtin_amdgcn_mfma_f32_32x32x16_bf16(kf2, qf[2], s, 0, 0, 0);
        s = __builtin_amdgcn_mfma_f32_32x32x16_bf16(kf3, qf[3], s, 0, 0, 0);
        __builtin_amdgcn_s_setprio(0);
        bf16x8 vf0 = *(const bf16x8*)&pt[2048];
        bf16x8 vf1 = *(const bf16x8*)&pt[2560];
        bf16x8 vf2 = *(const bf16x8*)&pt[3072];
        bf16x8 vf3 = *(const bf16x8*)&pt[3584];
        if (c0 + 31 >= cstart && c0 + 31 - cstart > i0) {
#pragma unroll
            for (int r = 0; r < 16; ++r) {
                int kvg = c0 + ((r & 3) + 8 * (r >> 2) + 4 * hi);
                if (kvg >= cstart && kvg - cstart > i0 + lq) s[r] = -FLT_MAX;
            }
        }
        float m8[8], m4[4];
#pragma unroll
        for (int r = 0; r < 8; ++r) m8[r] = fmaxf(s[2 * r], s[2 * r + 1]);
#pragma unroll
        for (int r = 0; r < 4; ++r) m4[r] = fmaxf(m8[2 * r], m8[2 * r + 1]);
        float vmax = fmaxf(fmaxf(m4[0], m4[1]), fmaxf(m4[2], m4[3]));
        vmax = fmaxf(vmax, __shfl_xor(vmax, 32));
        if (__any(vmax > mrun + 11.5f)) {
            float nm = fmaxf(mrun, vmax);
            float al = fast_exp2(mrun - nm);
#pragma unroll
            for (int r = 0; r < 16; ++r) { o0[r] *= al; o1[r] *= al; }
            lrun *= al;
            mrun = nm;
        }
        float p[16];
#pragma unroll
        for (int r = 0; r < 16; ++r) p[r] = fast_exp2(s[r] - mrun);
        float a8[8], a4[4];
#pragma unroll
        for (int r = 0; r < 8; ++r) a8[r] = p[2 * r] + p[2 * r + 1];
#pragma unroll
        for (int r = 0; r < 4; ++r) a4[r] = a8[2 * r] + a8[2 * r + 1];
        lrun += (a4[0] + a4[1]) + (a4[2] + a4[3]);
        unsigned pk[8];
#pragma unroll
        for (int k = 0; k < 8; ++k) {
            union { bf16 h[2]; unsigned u; } cv;
            cv.h[0] = __float2bfloat16(p[2 * k]);
            cv.h[1] = __float2bfloat16(p[2 * k + 1]);
            pk[k] = cv.u;
        }
        unsigned u0 = hi ? pk[0] : pk[2];
        unsigned u1 = hi ? pk[1] : pk[3];
        unsigned u2 = hi ? pk[4] : pk[6];
        unsigned u3 = hi ? pk[5] : pk[7];
        unsigned w0 = (unsigned)__shfl_xor((int)u0, 32);
        unsigned w1 = (unsigned)__shfl_xor((int)u1, 32);
        unsigned w2 = (unsigned)__shfl_xor((int)u2, 32);
        unsigned w3 = (unsigned)__shfl_xor((int)u3, 32);
        union { unsigned u[4]; bf16x8 v; } b0, b1;
        b0.u[0] = hi ? w0 : pk[0];
        b0.u[1] = hi ? w1 : pk[1];
        b0.u[2] = hi ? pk[2] : w0;
        b0.u[3] = hi ? pk[3] : w1;
        b1.u[0] = hi ? w2 : pk[4];
        b1.u[1] = hi ? w3 : pk[5];
        b1.u[2] = hi ? pk[6] : w2;
        b1.u[3] = hi ? pk[7] : w3;
        __builtin_amdgcn_s_setprio(1);
        o0 = __builtin_amdgcn_mfma_f32_32x32x16_bf16(vf0, b0.v, o0, 0, 0, 0);
        o1 = __builtin_amdgcn_mfma_f32_32x32x16_bf16(vf2, b0.v, o1, 0, 0, 0);
        o0 = __builtin_amdgcn_mfma_f32_32x32x16_bf16(vf1, b1.v, o0, 0, 0, 0);
        o1 = __builtin_amdgcn_mfma_f32_32x32x16_bf16(vf3, b1.v, o1, 0, 0, 0);
        __builtin_amdgcn_s_setprio(0);
    }
    // ---- 2-partial merge: waves (0,2) share qsel=0, (1,3) share qsel=1
    lrun += __shfl_xor(lrun, 32);
    if (lane < 32) { Msh[wave][lq] = mrun; Lsh[wave][lq] = lrun; }
    __syncthreads();
    float mp = Msh[wave ^ 2][lq];
    float M = fmaxf(mrun, mp);
    float scl = fast_exp2(mrun - M);
    if (half == 0) {
#pragma unroll
        for (int r = 0; r < 16; ++r) {
            int d = (r & 3) + 8 * (r >> 2) + 4 * hi;
            Osh[qsel][lq][d]      = o0[r] * scl;
            Osh[qsel][lq][d + 32] = o1[r] * scl;
        }
    }
    __syncthreads();
    if (half == 1) {
        float lt = lrun * scl + Lsh[wave ^ 2][lq] * fast_exp2(mp - M);
        float inv = 1.0f / lt;
#pragma unroll
        for (int r = 0; r < 16; ++r) {
            int d = (r & 3) + 8 * (r >> 2) + 4 * hi;
            o0[r] = o0[r] * scl + Osh[qsel][lq][d];
            o1[r] = o1[r] * scl + Osh[qsel][lq][d + 32];
        }
        size_t obase = ((size_t)bidx * NSEQ + tq) * DIM + head * HD;
#pragma unroll
        for (int dt = 0; dt < 2; ++dt)
#pragma unroll
            for (int a = 0; a < 4; ++a) {
                union { bf16 h[4]; uint2 u; } pkd;
                const f32x16& ov = dt ? o1 : o0;
#pragma unroll
                for (int i = 0; i < 4; ++i) pkd.h[i] = __float2bfloat16(ov[4 * a + i] * inv);
                *(uint2*)&Ob[obase + dt * 32 + 8 * a + 4 * hi] = pkd.u;
            }
    }
}

// ---------------------------------------------------------------- launch
extern "C" void kernel_launch(void* const* d_in, const int* in_sizes, int n_in,
                              void* d_out, int out_size, void* d_ws, size_t ws_size,
                              hipStream_t stream) {
    const float* x   = (const float*)d_in[0];
    const float* Wq  = (const float*)d_in[1];
    const float* Wkv = (const float*)d_in[2];
    const float* Wo  = (const float*)d_in[3];
    const float* bo  = (const float*)d_in[4];
    const float* Wo0 = (const float*)d_in[5];
    const float* bo0 = (const float*)d_in[6];
    float* out = (float*)d_out;

    char* ws = (char*)d_ws;
    size_t off = 0;
    auto alloc = [&](size_t bytes) { void* p = ws + off; off += (bytes + 255) & ~(size_t)255; return p; };
    float* cosT = (float*)alloc((size_t)NSEQ * 32 * 4);
    float* sinT = (float*)alloc((size_t)NSEQ * 32 * 4);
    bf16* Xb    = (bf16*)alloc((size_t)ROWS * DIM * 2);
    bf16* WqT   = (bf16*)alloc((size_t)DIM * DIM * 2);
    bf16* WkvT  = (bf16*)alloc((size_t)DIM * DIM * 2);
    bf16* WoT   = (bf16*)alloc((size_t)DIM * DIM * 2);
    bf16* Wo0T  = (bf16*)alloc((size_t)DIM * DIM * 2);
    bf16* Qb    = (bf16*)alloc((size_t)NC * NSEQ * HD * 2);
    bf16* KVf   = (bf16*)alloc((size_t)NC * 128 * 4096 * 2);
    bf16* Ob    = (bf16*)alloc((size_t)ROWS * DIM * 2);

    hipLaunchKernelGGL(k_prep, dim3(12800), dim3(256), 0, stream,
                       x, Xb, Wq, Wkv, Wo, Wo0, WqT, WkvT, WoT, Wo0T, cosT, sinT);

    hipLaunchKernelGGL(k_gemm_qkv, dim3(512), dim3(256), 0, stream, Xb, WqT, WkvT, cosT, sinT, Qb, KVf);

    hipLaunchKernelGGL(k_attn, dim3(2048), dim3(256), 0, stream, Qb, KVf, Ob);

    hipLaunchKernelGGL(k_gemm_out, dim3(1024), dim3(256), 0, stream, Ob, Wo0T, WoT, bo0, bo, out);
}